// Round 3
// baseline (342.732 us; speedup 1.0000x reference)
//
#include <hip/hip_runtime.h>
#include <math.h>

#define HIDDEN   2048
#define NEXPERT  64
#define TOPK     8
#define WAVES    8          // waves per router block, all share the same 64 tokens
#define KPW      128        // k per wave: 2048 / (2 k-half-blocks * 8 waves)
#define TILEK    32         // k staged to LDS per tile
#define LDSTR    36         // 32 + 4 pad: keeps 16B alignment, spreads banks
#define RSQRT_H  0.02209708691207961f   // 1/sqrt(2048)
#define NTOK     16384

// Wt[k][e] = proj_w[e][k] * scale[k] * H^-0.5  (transposed so a k-column of 64
// expert weights is 64 consecutive floats -> 4x s_load_dwordx16 per k)
__global__ __launch_bounds__(256) void prep_wt(
    const float* __restrict__ w, const float* __restrict__ scale,
    float* __restrict__ wt)
{
    int i = blockIdx.x * 256 + threadIdx.x;   // 131072 elements, coalesced writes
    int k = i >> 6, e = i & 63;
    wt[i] = w[e * HIDDEN + k] * scale[k] * RSQRT_H;
}

// lane = token (64 tokens/block), w delivered via scalar pipe (wave-uniform),
// h via coalesced global -> LDS -> per-lane ds_read_b128.
// Each wave accumulates acc[64 experts] fp32 over its 128-k slice; 8 waves
// combine deterministically in LDS; block stores one f32 partial per (t,e).
__global__ __launch_bounds__(512, 4) void router_main(
    const float* __restrict__ h, const float* __restrict__ wt,
    float* __restrict__ bp, float* __restrict__ ssp)
{
    __shared__ float lds[WAVES * 64 * LDSTR];   // 73728 B; combine bufs alias it

    const int tid  = (int)threadIdx.x;
    const int wave = __builtin_amdgcn_readfirstlane(tid >> 6);
    const int lane = tid & 63;
    const int t0   = blockIdx.x * 64;           // token group
    const int g    = blockIdx.y;                // k half (0/1)
    const int kw0  = g * 1024 + wave * KPW;     // this wave's k start

    float* wlds = &lds[wave * 64 * LDSTR];      // wave-private tile region

    float acc[NEXPERT];
#pragma unroll
    for (int e = 0; e < NEXPERT; ++e) acc[e] = 0.f;
    float ss = 0.f;

    for (int tile = 0; tile < KPW / TILEK; ++tile) {
        const int kc = kw0 + tile * TILEK;
        // stage 64 tokens x 32 k, coalesced (8 tokens x 8 float4-lanes per round)
#pragma unroll
        for (int i = 0; i < 8; ++i) {
            int tt = i * 8 + (lane >> 3);
            int kk = (lane & 7) * 4;
            float4 v = *(const float4*)(h + (size_t)(t0 + tt) * HIDDEN + kc + kk);
            *(float4*)(&wlds[tt * LDSTR + kk]) = v;
        }
        // DS pipe is in-order per wave: writes above complete before reads below
#pragma unroll
        for (int k4 = 0; k4 < TILEK; k4 += 4) {
            float4 h4 = *(const float4*)(&wlds[lane * LDSTR + k4]);
            const float* __restrict__ wk = wt + (size_t)(kc + k4) * NEXPERT; // uniform -> s_load
            ss = fmaf(h4.x, h4.x, ss);
            ss = fmaf(h4.y, h4.y, ss);
            ss = fmaf(h4.z, h4.z, ss);
            ss = fmaf(h4.w, h4.w, ss);
#pragma unroll
            for (int e = 0; e < NEXPERT; ++e) acc[e] = fmaf(wk[e],               h4.x, acc[e]);
#pragma unroll
            for (int e = 0; e < NEXPERT; ++e) acc[e] = fmaf(wk[NEXPERT + e],     h4.y, acc[e]);
#pragma unroll
            for (int e = 0; e < NEXPERT; ++e) acc[e] = fmaf(wk[2 * NEXPERT + e], h4.z, acc[e]);
#pragma unroll
            for (int e = 0; e < NEXPERT; ++e) acc[e] = fmaf(wk[3 * NEXPERT + e], h4.w, acc[e]);
        }
    }

    // ---- deterministic in-block combine: buf0 = w0+w2+w4+w6, buf1 = w1+w3+w5+w7
    __syncthreads();                       // all waves done with tile regions
    float* cbuf  = lds;                    // [2][64][65] = 8320 floats
    float* ssbuf = lds + 2 * 64 * 65;      // [8][64]     = 512 floats
    float* buf   = cbuf + (wave & 1) * (64 * 65);

    ssbuf[wave * 64 + lane] = ss;
    if (wave < 2) {
#pragma unroll
        for (int e = 0; e < NEXPERT; ++e) buf[lane * 65 + e] = acc[e];
    }
    __syncthreads();
    if (wave >= 2 && wave < 4) {
#pragma unroll
        for (int e = 0; e < NEXPERT; ++e) buf[lane * 65 + e] += acc[e];
    }
    __syncthreads();
    if (wave >= 4 && wave < 6) {
#pragma unroll
        for (int e = 0; e < NEXPERT; ++e) buf[lane * 65 + e] += acc[e];
    }
    __syncthreads();
    if (wave >= 6) {
#pragma unroll
        for (int e = 0; e < NEXPERT; ++e) buf[lane * 65 + e] += acc[e];
    }
    __syncthreads();

    // store block partial (4096 floats, coalesced) + per-token ss partial
    for (int i = tid; i < 64 * NEXPERT; i += 512) {
        int t = i >> 6, e = i & 63;
        float v = cbuf[t * 65 + e] + cbuf[64 * 65 + t * 65 + e];
        bp[((size_t)g * NTOK + t0 + t) * NEXPERT + e] = v;
    }
    if (tid < 64) {
        float s = 0.f;
#pragma unroll
        for (int w = 0; w < WAVES; ++w) s += ssbuf[w * 64 + tid];
        ssp[g * NTOK + t0 + tid] = s;
    }
}

// one wave per token, lane = expert: f64-sum the 2 partials, RMS factor,
// wave-ballot top-8 (ties -> lowest index), softmax-cancel weights, histogram.
__global__ __launch_bounds__(256) void finalize_kernel(
    const float* __restrict__ bp, const float* __restrict__ ssp,
    const float* __restrict__ pes,
    float* __restrict__ out_w, float* __restrict__ out_i, float* __restrict__ out_c)
{
    const int lane = (int)threadIdx.x & 63;
    const int wave = (int)threadIdx.x >> 6;
    const int t    = blockIdx.x * 4 + wave;

    __shared__ int hist[NEXPERT];
    if (threadIdx.x < NEXPERT) hist[threadIdx.x] = 0;
    __syncthreads();

    float b0 = bp[((size_t)0 * NTOK + t) * NEXPERT + lane];
    float b1 = bp[((size_t)1 * NTOK + t) * NEXPERT + lane];
    double d = (double)b0 + (double)b1;

    double sst = (double)ssp[t] + (double)ssp[NTOK + t];
    float r = (float)(1.0 / sqrt(sst * (1.0 / (double)HIDDEN) + 1e-6));
    float logit = (float)d * r;

    // iterative top-8: descending, exact ties -> lowest expert index
    float work = logit;
    float myval = 0.f; int myidx = 0; float m0 = 0.f;
#pragma unroll
    for (int i = 0; i < TOPK; ++i) {
        float mx = work;
#pragma unroll
        for (int off = 32; off; off >>= 1) mx = fmaxf(mx, __shfl_xor(mx, off, 64));
        unsigned long long msk = __ballot(work == mx);
        int src = __ffsll((long long)msk) - 1;
        if (i == 0) m0 = mx;
        if (lane == i) { myval = mx; myidx = src; }
        if (lane == src) work = -3.402823466e38f;
    }

    // softmax denominator cancels vs top-k renorm
    float ev = (lane < TOPK) ? expf(myval - m0) : 0.f;
    float es = ev;
    es += __shfl_xor(es, 1, 64);
    es += __shfl_xor(es, 2, 64);
    es += __shfl_xor(es, 4, 64);
    if (lane < TOPK) {
        float wgt = (ev / es) * pes[myidx];
        size_t o = (size_t)t * TOPK + lane;
        out_w[o] = wgt;
        out_i[o] = (float)myidx;   // whole d_out is read as float32
        atomicAdd(&hist[myidx], 1);
    }

    __syncthreads();
    if (threadIdx.x < NEXPERT)
        atomicAdd(&out_c[threadIdx.x], (float)hist[threadIdx.x]);
}

extern "C" void kernel_launch(void* const* d_in, const int* in_sizes, int n_in,
                              void* d_out, int out_size, void* d_ws, size_t ws_size,
                              hipStream_t stream) {
    const float* h     = (const float*)d_in[0];   // [4,4096,2048] f32
    const float* scale = (const float*)d_in[1];   // [2048] f32
    const float* w     = (const float*)d_in[2];   // [64,2048] f32
    const float* pes   = (const float*)d_in[3];   // [64] f32

    // workspace: Wt (512 KB) | bp 2x16384x64 f32 (8 MB) | ssp 2x16384 f32 (128 KB)
    float* wt  = (float*)d_ws;
    float* bp  = wt + (size_t)HIDDEN * NEXPERT;
    float* ssp = bp + (size_t)2 * NTOK * NEXPERT;

    float* out_w = (float*)d_out;                                  // [16384,8]
    float* out_i = (float*)d_out + (size_t)NTOK * TOPK;            // [16384,8] idx-as-f32
    float* out_c = (float*)d_out + (size_t)NTOK * TOPK * 2;        // [64]

    hipMemsetAsync(out_c, 0, NEXPERT * sizeof(float), stream);

    prep_wt<<<(NEXPERT * HIDDEN) / 256, 256, 0, stream>>>(w, scale, wt);

    // 256 token-groups x 2 k-halves, 512 threads (8 waves) each
    router_main<<<dim3(NTOK / 64, 2), 512, 0, stream>>>(h, wt, bp, ssp);

    finalize_kernel<<<NTOK / 4, 256, 0, stream>>>(bp, ssp, pes, out_w, out_i, out_c);
}

// Round 4
// 291.897 us; speedup vs baseline: 1.1742x; 1.1742x over previous
//
#include <hip/hip_runtime.h>
#include <math.h>

#define HIDDEN   2048
#define NEXPERT  64
#define TOPK     8
#define TILEK    32
#define LDSTR    36          // 36 % 32 == 4: measured conflict-free for b128 lane=token reads (R3)
#define RSQRT_H  0.02209708691207961f
#define NTOK     16384
#define EPW      8           // experts per wave (8 waves x 8 = 64)

// Wt2 layout [eg][k][8]: wave eg's weight stream is fully contiguous ->
// 2x s_load_dwordx16 per k4-step, perfect scalar-cache streaming.
__global__ __launch_bounds__(256) void prep_wt2(
    const float* __restrict__ w, const float* __restrict__ scale,
    float* __restrict__ wt2)
{
    int i = blockIdx.x * 256 + threadIdx.x;        // 131072
    int ep = i & 7;
    int k  = (i >> 3) & (HIDDEN - 1);
    int eg = i >> 14;
    wt2[i] = w[(eg * 8 + ep) * HIDDEN + k] * scale[k] * RSQRT_H;
}

// One block per 64 tokens, full k, 8 waves x 8 experts. Shared double-buffered
// h tile; weights via scalar pipe (32 floats / 64 fmac-cycles per wave).
// Logits finalized in-block: no partials, no second pass.
__global__ __launch_bounds__(512) void router_main(
    const float* __restrict__ h, const float* __restrict__ wt2,
    const float* __restrict__ pes,
    float* __restrict__ out_w, float* __restrict__ out_i, float* __restrict__ out_c)
{
    __shared__ float lds[2 * 64 * LDSTR];          // 4608 floats = 18 KB
    // epilogue aliases (used only after the k-loop + barrier):
    //   lg  = lds[0 .. 4159]   logits [64][65]
    //   lss = lds[4160..4223]  per-token sum-of-squares
    //   hist= lds[4224..4287]  (as int)

    const int tid  = (int)threadIdx.x;
    const int eg   = __builtin_amdgcn_readfirstlane(tid >> 6);  // wave id = expert group
    const int lane = tid & 63;
    const int t0   = (int)blockIdx.x * 64;

    // staging coords: thread -> (token tt, k-offset kk), 1 float4 each
    const int tt = tid >> 3;
    const int kk = (tid & 7) * 4;
    const float* __restrict__ hload = h + (size_t)(t0 + tt) * HIDDEN + kk;
    const int wtt = tt * LDSTR + kk;               // ds_write offset
    const int rdo = lane * LDSTR;                  // ds_read base (lane = token)

    const float* __restrict__ wbase = wt2 + (size_t)eg * (HIDDEN * EPW);

    double accd[EPW];
#pragma unroll
    for (int e = 0; e < EPW; ++e) accd[e] = 0.0;
    float ssl = 0.f;                               // this thread's k-slice sum-of-squares

    float4 v = *(const float4*)hload;              // prefetch tile 0

    for (int tile = 0; tile < HIDDEN / TILEK; ++tile) {
        float* buf = &lds[(tile & 1) * (64 * LDSTR)];
        *(float4*)(&buf[wtt]) = v;
        ssl = fmaf(v.x, v.x, ssl);
        ssl = fmaf(v.y, v.y, ssl);
        ssl = fmaf(v.z, v.z, ssl);
        ssl = fmaf(v.w, v.w, ssl);
        __syncthreads();                           // write -> read ordering (1 barrier/tile)
        if (tile < HIDDEN / TILEK - 1)
            v = *(const float4*)(hload + (tile + 1) * TILEK);   // hidden behind compute

        const float* __restrict__ wk0 = wbase + tile * (TILEK * EPW);
        float acc[EPW];
#pragma unroll
        for (int e = 0; e < EPW; ++e) acc[e] = 0.f;
#pragma unroll
        for (int k4 = 0; k4 < TILEK; k4 += 4) {
            float4 h4 = *(const float4*)(&buf[rdo + k4]);
            const float* __restrict__ wk = wk0 + k4 * EPW;      // uniform -> s_load
#pragma unroll
            for (int e = 0; e < EPW; ++e) acc[e] = fmaf(wk[e],           h4.x, acc[e]);
#pragma unroll
            for (int e = 0; e < EPW; ++e) acc[e] = fmaf(wk[EPW + e],     h4.y, acc[e]);
#pragma unroll
            for (int e = 0; e < EPW; ++e) acc[e] = fmaf(wk[2 * EPW + e], h4.z, acc[e]);
#pragma unroll
            for (int e = 0; e < EPW; ++e) acc[e] = fmaf(wk[3 * EPW + e], h4.w, acc[e]);
        }
        // fold 32-k fp32 chain into f64: keeps logits ordering-exact (R2-verified)
#pragma unroll
        for (int e = 0; e < EPW; ++e) accd[e] += (double)acc[e];
    }

    // ---- sum-of-squares: 8 staging threads per token, shuffle-combine
    ssl += __shfl_xor(ssl, 1, 64);
    ssl += __shfl_xor(ssl, 2, 64);
    ssl += __shfl_xor(ssl, 4, 64);

    __syncthreads();                               // k-loop fully done; LDS reusable
    float* lg   = lds;                             // [64][65]
    float* lss  = lds + 64 * 65;
    int*   hist = (int*)(lds + 64 * 65 + 64);
    if ((lane & 7) == 0) lss[eg * 8 + (lane >> 3)] = ssl;
    if (tid < NEXPERT) hist[tid] = 0;
    __syncthreads();

    // each lane: its token's RMS factor; write this wave's 8 logits
    {
        float s = lss[lane];
        float r = (float)(1.0 / sqrt((double)s * (1.0 / (double)HIDDEN) + 1e-6));
#pragma unroll
        for (int e = 0; e < EPW; ++e)
            lg[lane * 65 + eg * EPW + e] = (float)accd[e] * r;
    }
    __syncthreads();

    // ---- top-8 epilogue: wave eg handles tokens eg*8 .. eg*8+7 (lane = expert)
    for (int i = 0; i < 8; ++i) {
        const int tok = eg * 8 + i;
        float logit = lg[tok * 65 + lane];

        float work = logit;
        float myval = 0.f; int myidx = 0; float m0 = 0.f;
#pragma unroll
        for (int j = 0; j < TOPK; ++j) {
            float mx = work;
#pragma unroll
            for (int off = 32; off; off >>= 1) mx = fmaxf(mx, __shfl_xor(mx, off, 64));
            unsigned long long msk = __ballot(work == mx);
            int src = __ffsll((long long)msk) - 1;  // ties -> lowest index (jax)
            if (j == 0) m0 = mx;
            if (lane == j) { myval = mx; myidx = src; }
            if (lane == src) work = -3.402823466e38f;
        }

        float ev = (lane < TOPK) ? expf(myval - m0) : 0.f;
        float es = ev;
        es += __shfl_xor(es, 1, 64);
        es += __shfl_xor(es, 2, 64);
        es += __shfl_xor(es, 4, 64);
        if (lane < TOPK) {
            float wgt = (ev / es) * pes[myidx];
            size_t o = (size_t)(t0 + tok) * TOPK + lane;
            out_w[o] = wgt;
            out_i[o] = (float)myidx;               // d_out read as float32
            atomicAdd(&hist[myidx], 1);
        }
    }

    __syncthreads();
    if (tid < NEXPERT)
        atomicAdd(&out_c[tid], (float)hist[tid]);
}

extern "C" void kernel_launch(void* const* d_in, const int* in_sizes, int n_in,
                              void* d_out, int out_size, void* d_ws, size_t ws_size,
                              hipStream_t stream) {
    const float* h     = (const float*)d_in[0];   // [4,4096,2048] f32
    const float* scale = (const float*)d_in[1];   // [2048] f32
    const float* w     = (const float*)d_in[2];   // [64,2048] f32
    const float* pes   = (const float*)d_in[3];   // [64] f32

    float* wt2 = (float*)d_ws;                    // 512 KB

    float* out_w = (float*)d_out;                                  // [16384,8]
    float* out_i = (float*)d_out + (size_t)NTOK * TOPK;            // [16384,8] idx-as-f32
    float* out_c = (float*)d_out + (size_t)NTOK * TOPK * 2;        // [64]

    hipMemsetAsync(out_c, 0, NEXPERT * sizeof(float), stream);

    prep_wt2<<<(NEXPERT * HIDDEN) / 256, 256, 0, stream>>>(w, scale, wt2);

    // 256 blocks (1/CU) x 512 threads; full k per block, epilogue in-block
    router_main<<<NTOK / 64, 512, 0, stream>>>(h, wt2, pes, out_w, out_i, out_c);
}

// Round 5
// 254.764 us; speedup vs baseline: 1.3453x; 1.1458x over previous
//
#include <hip/hip_runtime.h>
#include <math.h>

#define HIDDEN   2048
#define NEXPERT  64
#define TOPK     8
#define TILEK    64
#define LDSTR    68          // 64 + 4 pad: ≡4 mod 32, same bank class as 36 (measured conflict-free R3/R4)
#define RSQRT_H  0.02209708691207961f
#define NTOK     16384
#define EPW      4           // experts per wave (16 waves x 4 = 64)

// Wt4 layout [eg(16)][k(2048)][4]: wave eg's weight stream fully contiguous ->
// 1x s_load_dwordx16 per k4-step, sequential scalar-cache streaming.
__global__ __launch_bounds__(256) void prep_wt4(
    const float* __restrict__ w, const float* __restrict__ scale,
    float* __restrict__ wt4)
{
    int i  = blockIdx.x * 256 + threadIdx.x;       // 131072
    int ep = i & 3;
    int k  = (i >> 2) & (HIDDEN - 1);
    int eg = i >> 13;
    wt4[i] = w[(eg * EPW + ep) * HIDDEN + k] * scale[k] * RSQRT_H;
}

// One block per 64 tokens, full k, 16 waves x 4 experts (1024 threads).
// 16 waves/CU (4/SIMD) hides the s_load/ds latency that stalled R4 (8 waves/CU,
// VALUBusy 25%, and L3-warm replays at identical dur -> pure latency-bound).
__global__ __launch_bounds__(1024) void router_main(
    const float* __restrict__ h, const float* __restrict__ wt4,
    const float* __restrict__ pes,
    float* __restrict__ out_w, float* __restrict__ out_i, float* __restrict__ out_c)
{
    __shared__ float lds[2 * 64 * LDSTR];          // 8704 floats = 34.8 KB
    // epilogue aliases (after k-loop + barrier): lg[64][65], lss[64], hist[64]

    const int tid  = (int)threadIdx.x;
    const int wave = __builtin_amdgcn_readfirstlane(tid >> 6);  // wave id = expert group
    const int lane = tid & 63;
    const int t0   = (int)blockIdx.x * 64;

    // staging: 64 tok x 64 k tile = 1024 float4, one per thread, coalesced
    const int tt = tid >> 4;                       // token row 0..63
    const int kk = (tid & 15) * 4;                 // k offset 0..60
    const float* __restrict__ hload = h + (size_t)(t0 + tt) * HIDDEN + kk;
    const int wtt = tt * LDSTR + kk;
    const int rdo = lane * LDSTR;                  // lane = token for ds_read

    const float* __restrict__ wbase = wt4 + (size_t)wave * (HIDDEN * EPW);

    double accd[EPW];
#pragma unroll
    for (int e = 0; e < EPW; ++e) accd[e] = 0.0;
    float ssl = 0.f;                               // this thread's k-slice sum-of-squares

    float4 v = *(const float4*)hload;              // prefetch tile 0

    for (int tile = 0; tile < HIDDEN / TILEK; ++tile) {     // 32 tiles
        float* buf = &lds[(tile & 1) * (64 * LDSTR)];
        *(float4*)(&buf[wtt]) = v;
        ssl = fmaf(v.x, v.x, ssl);
        ssl = fmaf(v.y, v.y, ssl);
        ssl = fmaf(v.z, v.z, ssl);
        ssl = fmaf(v.w, v.w, ssl);
        __syncthreads();                           // lgkmcnt(0)+s_barrier: write->read safe
        if (tile < HIDDEN / TILEK - 1)
            v = *(const float4*)(hload + (tile + 1) * TILEK);   // hidden behind compute

        const float* __restrict__ wk0 = wbase + tile * (TILEK * EPW);
        float acc[EPW];
#pragma unroll
        for (int e = 0; e < EPW; ++e) acc[e] = 0.f;
#pragma unroll
        for (int k4 = 0; k4 < TILEK; k4 += 4) {
            float4 h4 = *(const float4*)(&buf[rdo + k4]);
            const float* __restrict__ wk = wk0 + k4 * EPW;  // uniform -> s_load_dwordx16
#pragma unroll
            for (int e = 0; e < EPW; ++e) acc[e] = fmaf(wk[e],           h4.x, acc[e]);
#pragma unroll
            for (int e = 0; e < EPW; ++e) acc[e] = fmaf(wk[EPW + e],     h4.y, acc[e]);
#pragma unroll
            for (int e = 0; e < EPW; ++e) acc[e] = fmaf(wk[2 * EPW + e], h4.z, acc[e]);
#pragma unroll
            for (int e = 0; e < EPW; ++e) acc[e] = fmaf(wk[3 * EPW + e], h4.w, acc[e]);
        }
        // fold 64-k fp32 chain into f64: logits stay ordering-exact (~1.5e-9 err)
#pragma unroll
        for (int e = 0; e < EPW; ++e) accd[e] += (double)acc[e];
    }

    // ---- sum-of-squares: 16 staging threads per token row, width-16 shuffle
    ssl += __shfl_xor(ssl, 1, 16);
    ssl += __shfl_xor(ssl, 2, 16);
    ssl += __shfl_xor(ssl, 4, 16);
    ssl += __shfl_xor(ssl, 8, 16);

    __syncthreads();                               // k-loop fully done; LDS reusable
    float* lg   = lds;                             // [64][65]
    float* lss  = lds + 64 * 65;
    int*   hist = (int*)(lds + 64 * 65 + 64);
    if ((tid & 15) == 0) lss[tt] = ssl;            // one writer per token
    if (tid < NEXPERT) hist[tid] = 0;
    __syncthreads();

    // lane = token: RMS factor, write this wave's 4 logits
    {
        float s = lss[lane];
        float r = (float)(1.0 / sqrt((double)s * (1.0 / (double)HIDDEN) + 1e-6));
#pragma unroll
        for (int e = 0; e < EPW; ++e)
            lg[lane * 65 + wave * EPW + e] = (float)accd[e] * r;
    }
    __syncthreads();

    // ---- top-8 epilogue: wave w handles tokens w*4..w*4+3 (lane = expert)
    for (int i = 0; i < 4; ++i) {
        const int tok = wave * 4 + i;
        float logit = lg[tok * 65 + lane];

        float work = logit;
        float myval = 0.f; int myidx = 0; float m0 = 0.f;
#pragma unroll
        for (int j = 0; j < TOPK; ++j) {
            float mx = work;
#pragma unroll
            for (int off = 32; off; off >>= 1) mx = fmaxf(mx, __shfl_xor(mx, off, 64));
            unsigned long long msk = __ballot(work == mx);
            int src = __ffsll((long long)msk) - 1;  // ties -> lowest index (jax)
            if (j == 0) m0 = mx;
            if (lane == j) { myval = mx; myidx = src; }
            if (lane == src) work = -3.402823466e38f;
        }

        float ev = (lane < TOPK) ? expf(myval - m0) : 0.f;
        float es = ev;
        es += __shfl_xor(es, 1, 64);
        es += __shfl_xor(es, 2, 64);
        es += __shfl_xor(es, 4, 64);
        if (lane < TOPK) {
            float wgt = (ev / es) * pes[myidx];
            size_t o = (size_t)(t0 + tok) * TOPK + lane;
            out_w[o] = wgt;
            out_i[o] = (float)myidx;               // d_out read as float32
            atomicAdd(&hist[myidx], 1);
        }
    }

    __syncthreads();
    if (tid < NEXPERT)
        atomicAdd(&out_c[tid], (float)hist[tid]);
}

extern "C" void kernel_launch(void* const* d_in, const int* in_sizes, int n_in,
                              void* d_out, int out_size, void* d_ws, size_t ws_size,
                              hipStream_t stream) {
    const float* h     = (const float*)d_in[0];   // [4,4096,2048] f32
    const float* scale = (const float*)d_in[1];   // [2048] f32
    const float* w     = (const float*)d_in[2];   // [64,2048] f32
    const float* pes   = (const float*)d_in[3];   // [64] f32

    float* wt4 = (float*)d_ws;                    // 512 KB

    float* out_w = (float*)d_out;                                  // [16384,8]
    float* out_i = (float*)d_out + (size_t)NTOK * TOPK;            // [16384,8] idx-as-f32
    float* out_c = (float*)d_out + (size_t)NTOK * TOPK * 2;        // [64]

    hipMemsetAsync(out_c, 0, NEXPERT * sizeof(float), stream);

    prep_wt4<<<(NEXPERT * HIDDEN) / 256, 256, 0, stream>>>(w, scale, wt4);

    // 256 blocks (1/CU) x 1024 threads (16 waves, 4/SIMD): latency-hiding x2 vs R4
    router_main<<<NTOK / 64, 1024, 0, stream>>>(h, wt4, pes, out_w, out_i, out_c);
}

// Round 6
// 234.462 us; speedup vs baseline: 1.4618x; 1.0866x over previous
//
#include <hip/hip_runtime.h>
#include <math.h>

#define HIDDEN   2048
#define NEXPERT  64
#define TOPK     8
#define NTOK     16384
#define TOKB     16          // tokens per block (one 16-row M tile)
#define CHUNK    256         // k per LDS chunk
#define NCHUNK   8
#define ROWP     264         // 256 + 8 pad, ushorts (row stride 528 B, 16B-aligned)
#define RSQRT_H  0.02209708691207961
#define WSCALE   64.0f       // keeps f16 Wl split in normal range; undone in epilogue

typedef __attribute__((ext_vector_type(8))) _Float16 v8h;
typedef __attribute__((ext_vector_type(4))) float    v4f;

static __device__ __forceinline__ unsigned short f16b(float x) {
    return __builtin_bit_cast(unsigned short, (_Float16)x);   // v_cvt_f16_f32 (RNE)
}
static __device__ __forceinline__ float f16f(unsigned short u) {
    return (float)__builtin_bit_cast(_Float16, u);
}

// Weight prep into B-fragment order: wf[ks(64)][nt(4)][hl(2)][lane(64)][j(8)] f16.
// B[k][n]: n = nt*16 + (lane&15), k = ks*32 + (lane>>4)*8 + j.  v = w*scale*64.
__global__ __launch_bounds__(256) void prep_wf(
    const float* __restrict__ w, const float* __restrict__ scale,
    unsigned short* __restrict__ wf)
{
    int i    = blockIdx.x * 256 + threadIdx.x;   // 131072
    int j    = i & 7;
    int lane = (i >> 3) & 63;
    int nt   = (i >> 9) & 3;
    int ks   = i >> 11;
    int e    = nt * 16 + (lane & 15);
    int k    = ks * 32 + (lane >> 4) * 8 + j;
    float v  = w[e * HIDDEN + k] * scale[k] * WSCALE;
    unsigned short vh = f16b(v);
    unsigned short vl = f16b(v - f16f(vh));      // Dekker split: v - hi exact in f32
    size_t base = (((size_t)(ks * 4 + nt) * 2) * 64 + lane) * 8 + j;
    wf[base]       = vh;                          // hl=0
    wf[base + 512] = vl;                          // hl=1 (stride 64*8)
}

// 16 tokens/block, 256 thr (4 waves), full k. Split-f16 MFMA:
// logits_raw = Xh*Wh + Xh*Wl + Xl*Wh  (error ~2e-9 after rescale — ordering-exact).
// Waves split the 8 k-steps per chunk (2 each); 4 partials combined in LDS.
__global__ __launch_bounds__(256, 4) void router_main(
    const float* __restrict__ h, const unsigned short* __restrict__ wf,
    const float* __restrict__ pes,
    float* __restrict__ out_w, float* __restrict__ out_i, float* __restrict__ out_c)
{
    // [buf0: Xh(16x264) Xl(16x264)][buf1: same] | lss[16] | hist[64]
    __shared__ __align__(16) char smem[34112];
    unsigned short* Xb0 = (unsigned short*)smem;          // 8448 ushorts per buffer
    float* lss = (float*)(smem + 33792);
    int*   hist = (int*)(smem + 33856);
    float* lg  = (float*)smem;                            // alias after k-loop: [4][16][65]

    const int tid  = (int)threadIdx.x;
    const int w    = __builtin_amdgcn_readfirstlane(tid >> 6);   // wave 0..3
    const int lane = tid & 63;
    const int m    = lane & 15;                                   // A row / D col idx
    const int quad = lane >> 4;
    const int t0   = (int)blockIdx.x * TOKB;

    if (tid < NEXPERT) hist[tid] = 0;

    // staging map: idx = i*256+tid -> token t = i*4 + w (wave-contiguous 1KB rows)
    const int aoff = m * ROWP + quad * 8;                 // A-frag base (ushorts)

    v4f acc[4];
#pragma unroll
    for (int nt = 0; nt < 4; ++nt) acc[nt] = (v4f)0.f;
    float ss[4] = {0.f, 0.f, 0.f, 0.f};
    float4 st[4];

    // prefetch + flush chunk 0
#pragma unroll
    for (int i = 0; i < 4; ++i) {
        int idx = i * 256 + tid, t = idx >> 6, kq = idx & 63;
        st[i] = *(const float4*)(h + (size_t)(t0 + t) * HIDDEN + kq * 4);
    }
#pragma unroll
    for (int i = 0; i < 4; ++i) {
        int idx = i * 256 + tid, t = idx >> 6, kq = idx & 63;
        float4 v = st[i];
        ss[i] = fmaf(v.x, v.x, fmaf(v.y, v.y, fmaf(v.z, v.z, fmaf(v.w, v.w, ss[i]))));
        unsigned short h0 = f16b(v.x), h1 = f16b(v.y), h2 = f16b(v.z), h3 = f16b(v.w);
        unsigned short l0 = f16b(v.x - f16f(h0)), l1 = f16b(v.y - f16f(h1));
        unsigned short l2 = f16b(v.z - f16f(h2)), l3 = f16b(v.w - f16f(h3));
        uint2 hp = make_uint2((unsigned)h0 | ((unsigned)h1 << 16),
                              (unsigned)h2 | ((unsigned)h3 << 16));
        uint2 lp = make_uint2((unsigned)l0 | ((unsigned)l1 << 16),
                              (unsigned)l2 | ((unsigned)l3 << 16));
        *(uint2*)(&Xb0[t * ROWP + kq * 4])        = hp;
        *(uint2*)(&Xb0[4224 + t * ROWP + kq * 4]) = lp;
    }

    for (int c = 0; c < NCHUNK; ++c) {
        __syncthreads();   // buf[c&1] ready; buf[(c+1)&1] free (readers of c-1 done)
        unsigned short* buf = Xb0 + (c & 1) * 8448;
        unsigned short* nbuf = Xb0 + ((c + 1) & 1) * 8448;

        if (c < NCHUNK - 1) {          // issue next chunk's global loads first
#pragma unroll
            for (int i = 0; i < 4; ++i) {
                int idx = i * 256 + tid, t = idx >> 6, kq = idx & 63;
                st[i] = *(const float4*)(h + (size_t)(t0 + t) * HIDDEN
                                           + (c + 1) * CHUNK + kq * 4);
            }
        }

        // compute this chunk: wave w owns k-steps {2w, 2w+1} (32 k each)
#pragma unroll
        for (int s = 0; s < 2; ++s) {
            const int ksl = 2 * w + s;
            const int ksg = c * 8 + ksl;
            v8h ah = *(const v8h*)(&buf[aoff + ksl * 32]);
            v8h al = *(const v8h*)(&buf[4224 + aoff + ksl * 32]);
#pragma unroll
            for (int nt = 0; nt < 4; ++nt) {
                const unsigned short* bp =
                    wf + (((size_t)(ksg * 4 + nt) * 2) * 64 + lane) * 8;
                v8h bh = *(const v8h*)bp;
                v8h bl = *(const v8h*)(bp + 512);
                acc[nt] = __builtin_amdgcn_mfma_f32_16x16x32_f16(ah, bh, acc[nt], 0, 0, 0);
                acc[nt] = __builtin_amdgcn_mfma_f32_16x16x32_f16(ah, bl, acc[nt], 0, 0, 0);
                acc[nt] = __builtin_amdgcn_mfma_f32_16x16x32_f16(al, bh, acc[nt], 0, 0, 0);
            }
        }

        if (c < NCHUNK - 1) {          // convert + stage into the other buffer
#pragma unroll
            for (int i = 0; i < 4; ++i) {
                int idx = i * 256 + tid, t = idx >> 6, kq = idx & 63;
                float4 v = st[i];
                ss[i] = fmaf(v.x, v.x, fmaf(v.y, v.y, fmaf(v.z, v.z, fmaf(v.w, v.w, ss[i]))));
                unsigned short h0 = f16b(v.x), h1 = f16b(v.y), h2 = f16b(v.z), h3 = f16b(v.w);
                unsigned short l0 = f16b(v.x - f16f(h0)), l1 = f16b(v.y - f16f(h1));
                unsigned short l2 = f16b(v.z - f16f(h2)), l3 = f16b(v.w - f16f(h3));
                uint2 hp = make_uint2((unsigned)h0 | ((unsigned)h1 << 16),
                                      (unsigned)h2 | ((unsigned)h3 << 16));
                uint2 lp = make_uint2((unsigned)l0 | ((unsigned)l1 << 16),
                                      (unsigned)l2 | ((unsigned)l3 << 16));
                *(uint2*)(&nbuf[t * ROWP + kq * 4])        = hp;
                *(uint2*)(&nbuf[4224 + t * ROWP + kq * 4]) = lp;
            }
        }
    }

    // ---- sum-of-squares: thread's tokens are {4i + w}; full-wave reduce each
#pragma unroll
    for (int i = 0; i < 4; ++i) {
        float s = ss[i];
#pragma unroll
        for (int off = 32; off; off >>= 1) s += __shfl_xor(s, off, 64);
        if (lane == 0) lss[i * 4 + w] = s;
    }
    __syncthreads();                    // k-loop + lss done; LDS bufs now dead -> lg alias

    // write raw partials: D row=(quad*4+reg)=token, col=(lane&15)+nt*16=expert
#pragma unroll
    for (int nt = 0; nt < 4; ++nt)
#pragma unroll
        for (int r = 0; r < 4; ++r) {
            int tl = quad * 4 + r;
            lg[(w * 16 + tl) * 65 + nt * 16 + m] = acc[nt][r];
        }
    __syncthreads();

    // ---- top-8 epilogue (R2-verified): wave w handles tokens w*4..w*4+3
    for (int i = 0; i < 4; ++i) {
        const int tok = w * 4 + i;
        float lsum = (lg[tok * 65 + lane]          + lg[1040 + tok * 65 + lane])
                   + (lg[2080 + tok * 65 + lane]   + lg[3120 + tok * 65 + lane]);
        double sst = (double)lss[tok];
        double rr  = 1.0 / sqrt(sst * (1.0 / (double)HIDDEN) + 1e-6);
        float logit = (float)((double)lsum * rr * (RSQRT_H / (double)WSCALE));

        float work = logit;
        float myval = 0.f; int myidx = 0; float m0 = 0.f;
#pragma unroll
        for (int j = 0; j < TOPK; ++j) {
            float mx = work;
#pragma unroll
            for (int off = 32; off; off >>= 1) mx = fmaxf(mx, __shfl_xor(mx, off, 64));
            unsigned long long msk = __ballot(work == mx);
            int src = __ffsll((long long)msk) - 1;   // ties -> lowest index (jax)
            if (j == 0) m0 = mx;
            if (lane == j) { myval = mx; myidx = src; }
            if (lane == src) work = -3.402823466e38f;
        }

        float ev = (lane < TOPK) ? expf(myval - m0) : 0.f;
        float es = ev;
        es += __shfl_xor(es, 1, 64);
        es += __shfl_xor(es, 2, 64);
        es += __shfl_xor(es, 4, 64);
        if (lane < TOPK) {
            float wgt = (ev / es) * pes[myidx];
            size_t o = (size_t)(t0 + tok) * TOPK + lane;
            out_w[o] = wgt;
            out_i[o] = (float)myidx;                 // d_out read as float32
            atomicAdd(&hist[myidx], 1);
        }
    }

    __syncthreads();
    if (tid < NEXPERT)
        atomicAdd(&out_c[tid], (float)hist[tid]);    // counts are exact small ints
}

extern "C" void kernel_launch(void* const* d_in, const int* in_sizes, int n_in,
                              void* d_out, int out_size, void* d_ws, size_t ws_size,
                              hipStream_t stream) {
    const float* h     = (const float*)d_in[0];   // [4,4096,2048] f32
    const float* scale = (const float*)d_in[1];   // [2048] f32
    const float* w     = (const float*)d_in[2];   // [64,2048] f32
    const float* pes   = (const float*)d_in[3];   // [64] f32

    unsigned short* wf = (unsigned short*)d_ws;   // 512 KB f16 fragment bank

    float* out_w = (float*)d_out;                                  // [16384,8]
    float* out_i = (float*)d_out + (size_t)NTOK * TOPK;            // [16384,8] idx-as-f32
    float* out_c = (float*)d_out + (size_t)NTOK * TOPK * 2;        // [64]

    hipMemsetAsync(out_c, 0, NEXPERT * sizeof(float), stream);

    prep_wf<<<512, 256, 0, stream>>>(w, scale, wf);

    // 1024 blocks (4/CU, 16 waves/CU) x 256 thr
    router_main<<<NTOK / TOKB, 256, 0, stream>>>(h, wf, pes, out_w, out_i, out_c);
}